// Round 12
// baseline (21414.639 us; speedup 1.0000x reference)
//
#include <hip/hip_runtime.h>
#include <math.h>

#define B_    512
#define T_    512
#define H_    256
#define DIN_  64
#define OL_   8
#define DOUT_ 64

#define CBv   128
#define HSTR  32768          // CBv*256 u32 per henc slot

typedef unsigned short u16;
typedef unsigned int u32;
typedef unsigned long long ull;
typedef __attribute__((ext_vector_type(8))) short short8;   // 8 bf16 (MFMA A/B frag)
typedef __attribute__((ext_vector_type(4))) float f32x4;    // MFMA C/D frag (16x16)

static __device__ __forceinline__ float sigm(float x){ return 1.0f/(1.0f + expf(-x)); }
static __device__ __forceinline__ float bf2f(u16 h){
  u32 u = ((u32)h) << 16; float f; __builtin_memcpy(&f, &u, 4); return f;
}
static __device__ __forceinline__ u16 f2bf(float f){        // RNE
  u32 u; __builtin_memcpy(&u, &f, 4);
  u = (u + 0x7fffu + ((u >> 16) & 1u)) >> 16;
  return (u16)u;
}
static __device__ __forceinline__ u32 packhl(float f){      // hi<<16 | lo
  u16 h = f2bf(f);
  u16 lo = f2bf(f - bf2f(h));
  return ((u32)h << 16) | (u32)lo;
}
static __device__ __forceinline__ float unpackhl(u32 w){
  return bf2f((u16)(w >> 16)) + bf2f((u16)(w & 0xffff));
}
static __device__ __forceinline__ u32 al(const u32* p){
  return __hip_atomic_load(p, __ATOMIC_RELAXED, __HIP_MEMORY_SCOPE_AGENT);
}
static __device__ __forceinline__ void as_(u32* p, u32 v){
  __hip_atomic_store(p, v, __ATOMIC_RELAXED, __HIP_MEMORY_SCOPE_AGENT);
}

// ---------------------------------------------------------------------------
// Weight preps (unchanged, proven)
// ---------------------------------------------------------------------------
__global__ void k_wpt(const float* __restrict__ inW, const float* __restrict__ Wih,
                      float* __restrict__ WpT)
{
  int gid = blockIdx.x * 256 + threadIdx.x;   // 65536
  int c = gid >> 6, d = gid & 63;
  const float* wr = Wih + c * H_;
  const float* ir = inW + d * H_;
  float acc = 0.f;
  #pragma unroll 4
  for (int e = 0; e < H_; e += 4) {
    float4 av = *(const float4*)(ir + e);
    float4 bv = *(const float4*)(wr + e);
    acc += av.x*bv.x + av.y*bv.y + av.z*bv.z + av.w*bv.w;
  }
  WpT[c*64 + d] = acc;
}

__global__ void k_bp(const float* __restrict__ inb, const float* __restrict__ Wih,
                     const float* __restrict__ bih, const float* __restrict__ bhh,
                     float* __restrict__ bp)
{
  int c = blockIdx.x * 256 + threadIdx.x;   // 1024
  const float* wr = Wih + c * H_;
  float acc = bih[c] + bhh[c];
  for (int e = 0; e < H_; ++e) acc += inb[e] * wr[e];
  bp[c] = acc;
}

__global__ void k_dwt(const float* __restrict__ dWih, float* __restrict__ dWt)
{
  int gid = blockIdx.x * 256 + threadIdx.x;   // 393216
  int j = gid >> 9, k = gid & 511;
  int row = (j < 256) ? j : (j + 256);
  dWt[k*768 + j] = dWih[row*512 + k];
}

__global__ void k_wall(const float* __restrict__ wWs, const float* __restrict__ wWl,
                       const float* __restrict__ uWs, const float* __restrict__ uWl,
                       const float* __restrict__ vWs, u16* __restrict__ outb)
{
  int lyr = blockIdx.y;
  const float* W = (lyr < 3)  ? wWs + lyr*65536
                 : (lyr == 3) ? wWl
                 : (lyr < 7)  ? uWs + (lyr-4)*65536
                 : (lyr == 7) ? uWl
                 :              vWs + (lyr-8)*65536;
  u16* out = outb + (size_t)lyr*131072;
  int gid = blockIdx.x * 256 + threadIdx.x;   // 65536
  int k = gid & 255, n = gid >> 8;
  float v = W[k*256 + n];
  int s = k >> 5, j = k & 7;
  int lane = (((k >> 3) & 3) << 4) | (n & 15);
  int fl = ((s*16) + (n >> 4))*512 + lane*8 + j;
  u16 h = f2bf(v);
  out[fl] = h;
  out[65536 + fl] = f2bf(v - bf2f(h));
}

__global__ void k_whhfl(const float* __restrict__ Whh, u16* __restrict__ out)
{
  int gid = blockIdx.x * 256 + threadIdx.x;   // 262144
  int j = gid & 7, l = (gid >> 3) & 63, ctg = (gid >> 9) & 63, s = gid >> 15;
  int k = s*32 + (l >> 4)*8 + j;
  int wv = ctg >> 2, g = ctg & 3;
  int row = g*256 + wv*16 + (l & 15);
  float v = Whh[row*256 + k];
  int fl = (s*64 + ctg)*512 + l*8 + j;
  u16 h = f2bf(v);
  out[fl] = h;
  out[262144 + fl] = f2bf(v - bf2f(h));
}

__global__ void k_wpfl(const float* __restrict__ WpT, u16* __restrict__ out)
{
  int gid = blockIdx.x * 256 + threadIdx.x;   // 65536
  int j = gid & 7, l = (gid >> 3) & 63, ctg = (gid >> 9) & 63, s = gid >> 15;
  int k = s*32 + (l >> 4)*8 + j;              // < 64
  int wv = ctg >> 2, g = ctg & 3;
  int row = g*256 + wv*16 + (l & 15);
  float v = WpT[row*64 + k];
  int fl = (s*64 + ctg)*512 + l*8 + j;
  u16 h = f2bf(v);
  out[fl] = h;
  out[65536 + fl] = f2bf(v - bf2f(h));
}

// ---------------------------------------------------------------------------
// Clustered persistent encoder, DATA-AS-FLAG (r9, proven; unchanged).
// grid = (CBv/16, 8, NC).
// ---------------------------------------------------------------------------
__global__ __launch_bounds__(256,1) void k_enc(
    const float* __restrict__ x, const u16* __restrict__ whhFL,
    const u16* __restrict__ wpFL, const float* __restrict__ bp,
    u32* __restrict__ henc)
{
  __shared__ float G[2][16][32][4];
  const int tid = threadIdx.x, l = tid & 63, wv = tid >> 6;
  const int lr = l & 15, lk = l >> 4;
  const int rg = blockIdx.x, bg = blockIdx.y, z = blockIdx.z;
  const int ug2 = wv >> 1;
  const int g0 = (wv & 1) * 2;
  const int u16g = bg*2 + ug2;

  short8 whH[8][2], whL[8][2], wpH[2][2], wpL[2][2];
  #pragma unroll
  for (int s = 0; s < 8; ++s)
    #pragma unroll
    for (int c = 0; c < 2; ++c) {
      int ctg = u16g*4 + g0 + c;
      whH[s][c] = *(const short8*)(whhFL + ((size_t)(s*64 + ctg))*512 + l*8);
      whL[s][c] = *(const short8*)(whhFL + 262144 + ((size_t)(s*64 + ctg))*512 + l*8);
    }
  #pragma unroll
  for (int s = 0; s < 2; ++s)
    #pragma unroll
    for (int c = 0; c < 2; ++c) {
      int ctg = u16g*4 + g0 + c;
      wpH[s][c] = *(const short8*)(wpFL + ((size_t)(s*64 + ctg))*512 + l*8);
      wpL[s][c] = *(const short8*)(wpFL + 65536 + ((size_t)(s*64 + ctg))*512 + l*8);
    }
  const int ul = tid & 31, er0 = tid >> 5;
  float bb[4];
  #pragma unroll
  for (int g = 0; g < 4; ++g) bb[g] = bp[g*256 + bg*32 + ul];
  float cs[2] = {0.f, 0.f};

  u32* hz = henc + (size_t)z * (size_t)(T_+1) * HSTR;
  const float* xrow = x + ((size_t)(z*CBv + rg*16 + lr)*T_)*DIN_ + lk*8;

  for (int t = 0; t < T_; ++t) {
    float4 xv0 = *(const float4*)(xrow);
    float4 xv1 = *(const float4*)(xrow + 4);
    float4 xv2 = *(const float4*)(xrow + 32);
    float4 xv3 = *(const float4*)(xrow + 36);
    xrow += DIN_;

    const ull* hb = (const ull*)(hz + (size_t)t*HSTR + (size_t)(rg*16 + lr)*256);
    ull hq[8][4];
    #pragma unroll
    for (int s = 0; s < 8; ++s)
      #pragma unroll
      for (int q = 0; q < 4; ++q)
        hq[s][q] = __hip_atomic_load(hb + s*16 + lk*4 + q,
                                     __ATOMIC_RELAXED, __HIP_MEMORY_SCOPE_AGENT);
    if (t) {
      for (;;) {
        bool ok = true;
        #pragma unroll
        for (int s = 0; s < 8; ++s)
          #pragma unroll
          for (int q = 0; q < 4; ++q) {
            u32 a = (u32)hq[s][q], b = (u32)(hq[s][q] >> 32);
            ok = ok && (a != 0u) && (b != 0u);
          }
        if (__all(ok)) break;
        __builtin_amdgcn_s_sleep(1);
        #pragma unroll
        for (int s = 0; s < 8; ++s)
          #pragma unroll
          for (int q = 0; q < 4; ++q)
            hq[s][q] = __hip_atomic_load(hb + s*16 + lk*4 + q,
                                         __ATOMIC_RELAXED, __HIP_MEMORY_SCOPE_AGENT);
      }
    }

    f32x4 acc[2];
    acc[0] = (f32x4){0.f,0.f,0.f,0.f};
    acc[1] = (f32x4){0.f,0.f,0.f,0.f};

    #pragma unroll
    for (int s = 0; s < 2; ++s) {
      float vv[8];
      if (s == 0) { vv[0]=xv0.x;vv[1]=xv0.y;vv[2]=xv0.z;vv[3]=xv0.w;vv[4]=xv1.x;vv[5]=xv1.y;vv[6]=xv1.z;vv[7]=xv1.w; }
      else        { vv[0]=xv2.x;vv[1]=xv2.y;vv[2]=xv2.z;vv[3]=xv2.w;vv[4]=xv3.x;vv[5]=xv3.y;vv[6]=xv3.z;vv[7]=xv3.w; }
      short8 ah, al2;
      #pragma unroll
      for (int j = 0; j < 8; ++j) {
        u16 h = f2bf(vv[j]);
        ah[j] = (short)h;
        al2[j] = (short)f2bf(vv[j] - bf2f(h));
      }
      #pragma unroll
      for (int c = 0; c < 2; ++c) {
        acc[c] = __builtin_amdgcn_mfma_f32_16x16x32_bf16(ah,  wpH[s][c], acc[c], 0,0,0);
        acc[c] = __builtin_amdgcn_mfma_f32_16x16x32_bf16(al2, wpH[s][c], acc[c], 0,0,0);
        acc[c] = __builtin_amdgcn_mfma_f32_16x16x32_bf16(ah,  wpL[s][c], acc[c], 0,0,0);
      }
    }
    #pragma unroll
    for (int s = 0; s < 8; ++s) {
      short8 ah, al2;
      #pragma unroll
      for (int q = 0; q < 4; ++q) {
        u32 w0 = (u32)hq[s][q], w1 = (u32)(hq[s][q] >> 32);
        ah[q*2]   = (short)(w0 >> 16); al2[q*2]   = (short)(w0 & 0xffff);
        ah[q*2+1] = (short)(w1 >> 16); al2[q*2+1] = (short)(w1 & 0xffff);
      }
      #pragma unroll
      for (int c = 0; c < 2; ++c) {
        acc[c] = __builtin_amdgcn_mfma_f32_16x16x32_bf16(ah,  whH[s][c], acc[c], 0,0,0);
        acc[c] = __builtin_amdgcn_mfma_f32_16x16x32_bf16(al2, whH[s][c], acc[c], 0,0,0);
        acc[c] = __builtin_amdgcn_mfma_f32_16x16x32_bf16(ah,  whL[s][c], acc[c], 0,0,0);
      }
    }

    const int p = t & 1;
    #pragma unroll
    for (int c = 0; c < 2; ++c)
      #pragma unroll
      for (int j = 0; j < 4; ++j)
        G[p][lk*4 + j][ug2*16 + lr][g0 + c] = acc[c][j];
    __syncthreads();

    #pragma unroll
    for (int pp = 0; pp < 2; ++pp) {
      int row = er0 + pp*8;
      float4 gq = *(const float4*)&G[p][row][ul][0];
      float gi = gq.x + bb[0], gf = gq.y + bb[1];
      float gg = gq.z + bb[2], go = gq.w + bb[3];
      float cn = sigm(gf)*cs[pp] + sigm(gi)*tanhf(gg);
      float hn = sigm(go)*tanhf(cn);
      cs[pp] = cn;
      as_(hz + (size_t)(t+1)*HSTR + (size_t)(rg*16 + row)*256 + bg*32 + ul,
          packhl(hn) | 1u);
    }
  }
}

// ---------------------------------------------------------------------------
// MLP layer-loop core, 512 thr = 8 waves (2 row-groups x 4 col-groups).
// act: [64][256] u32 packhl, chunk-swizzled. Leaves final activations in act.
// ---------------------------------------------------------------------------
static __device__ __forceinline__ void mlp_core(
    u32* act, const u16* wFL, const float* bs, const float* bl,
    int L, int nbs, bool lastRelu, int tid)
{
  const int l = tid & 63, w = tid >> 6;
  const int rg = w >> 2, cg = w & 3;
  const int lr = l & 15, lk = l >> 4;
  const int wrow = rg*32;
  f32x4 acc[2][4];
  for (int lyr = 0; lyr < L; ++lyr) {
    __syncthreads();
    const u16* wb = wFL + (size_t)lyr*131072;
    #pragma unroll
    for (int rt = 0; rt < 2; ++rt)
      #pragma unroll
      for (int ct = 0; ct < 4; ++ct) acc[rt][ct] = (f32x4){0.f,0.f,0.f,0.f};

    short8 bh[2][4], blo[2][4];
    #pragma unroll
    for (int ct = 0; ct < 4; ++ct) {
      const u16* bfp = wb + ((size_t)(cg*4 + ct))*512 + l*8;
      bh[0][ct]  = *(const short8*)bfp;
      blo[0][ct] = *(const short8*)(bfp + 65536);
    }
    #pragma unroll
    for (int s = 0; s < 8; ++s) {
      const int pb = s & 1, nb = pb ^ 1;
      if (s < 7) {
        #pragma unroll
        for (int ct = 0; ct < 4; ++ct) {
          const u16* bfp = wb + ((size_t)((s+1)*16 + cg*4 + ct))*512 + l*8;
          bh[nb][ct]  = *(const short8*)bfp;
          blo[nb][ct] = *(const short8*)(bfp + 65536);
        }
      }
      short8 ah[2], al2[2];
      #pragma unroll
      for (int rt = 0; rt < 2; ++rt) {
        int row = wrow + rt*16 + lr;
        int cc = s*8 + lk*2;
        const u32* base = act + row*256;
        uint4 d0 = *(const uint4*)(base + (((cc    ) ^ (row & 7)) << 2));
        uint4 d1 = *(const uint4*)(base + (((cc + 1) ^ (row & 7)) << 2));
        u32 q[8] = {d0.x,d0.y,d0.z,d0.w,d1.x,d1.y,d1.z,d1.w};
        #pragma unroll
        for (int j = 0; j < 8; ++j) {
          ah[rt][j]  = (short)(q[j] >> 16);
          al2[rt][j] = (short)(q[j] & 0xffff);
        }
      }
      #pragma unroll
      for (int ct = 0; ct < 4; ++ct)
        #pragma unroll
        for (int rt = 0; rt < 2; ++rt) {
          acc[rt][ct] = __builtin_amdgcn_mfma_f32_16x16x32_bf16(ah[rt],  bh[pb][ct],  acc[rt][ct], 0,0,0);
          acc[rt][ct] = __builtin_amdgcn_mfma_f32_16x16x32_bf16(al2[rt], bh[pb][ct],  acc[rt][ct], 0,0,0);
          acc[rt][ct] = __builtin_amdgcn_mfma_f32_16x16x32_bf16(ah[rt],  blo[pb][ct], acc[rt][ct], 0,0,0);
        }
    }
    const float* bptr = (lyr < nbs) ? (bs + lyr*256) : bl;
    const bool dorelu = (lyr < L-1) || lastRelu;
    #pragma unroll
    for (int ct = 0; ct < 4; ++ct) {
      float bv = bptr[cg*64 + ct*16 + lr];
      #pragma unroll
      for (int rt = 0; rt < 2; ++rt)
        #pragma unroll
        for (int g = 0; g < 4; ++g) {
          float xv = acc[rt][ct][g] + bv;
          acc[rt][ct][g] = dorelu ? fmaxf(xv, 0.f) : xv;
        }
    }
    __syncthreads();
    #pragma unroll
    for (int ct = 0; ct < 4; ++ct) {
      int n = cg*64 + ct*16 + lr;
      #pragma unroll
      for (int rt = 0; rt < 2; ++rt)
        #pragma unroll
        for (int g = 0; g < 4; ++g) {
          int row = wrow + rt*16 + lk*4 + g;
          act[row*256 + (((n >> 2) ^ (row & 7)) << 2) + (n & 3)] = packhl(acc[rt][ct][g]);
        }
    }
  }
  __syncthreads();
}

// ---------------------------------------------------------------------------
// MEGA decode kernel v2, 512 thr, 128KB LDS (act 64KB + usL 64KB):
//  - u-MLP computed LOCALLY per block (its us-half) into usL: no usb/usflag.
//  - whsP eliminated: w-MLP recomputed inside the v-stage each step
//    (stage enc -> 4 w-layers -> tanh(+usL) -> 7 v-layers).
//  - attn / cell+outproj as r11 (proven).
// ---------------------------------------------------------------------------
__global__ __launch_bounds__(512,1) void k_dec_all(
    const u32* __restrict__ henc, const u16* __restrict__ mlpFL,
    const float* __restrict__ wbs, const float* __restrict__ wbl,
    const float* __restrict__ ubs, const float* __restrict__ ubl,
    const float* __restrict__ vbs, const float* __restrict__ vWl,
    const float* __restrict__ vbl,
    const float* __restrict__ dWt, const float* __restrict__ dbih,
    const float* __restrict__ dbhh,
    const float* __restrict__ oW, const float* __restrict__ ob,
    u32* __restrict__ eS, u32* __restrict__ ctxS, u32* __restrict__ sS,
    float* __restrict__ outc)
{
  extern __shared__ u32 act[];            // [16384] act + [16384] usL
  __shared__ float red[8], red2[8];
  const int bid = blockIdx.x, tid = threadIdx.x;
  u32* usL = act + 16384;
  const u16* wFLw = mlpFL;
  const u16* wFLu = mlpFL + 4*131072;
  const u16* wFLv = mlpFL + 8*131072;
  const int half = bid & 1;
  float sprev[4] = {0.f, 0.f, 0.f, 0.f};

  // ======== decode steps ========
  for (int s = 0; s < OL_; ++s) {
    // ---- u-phase: ALL blocks compute their us-half locally
    __syncthreads();                      // prior-step LDS uses complete
    for (int i = tid; i < 4096; i += 512) {
      int row = i >> 6, c16 = i & 63;
      uint4 pk;
      if (s) {
        const u32* sp = sS + (size_t)s*32768 + (size_t)(half*64 + row)*256 + c16*4;
        u32 w0 = al(sp), w1 = al(sp+1), w2 = al(sp+2), w3 = al(sp+3);
        while (!(w0 && w1 && w2 && w3)) {
          __builtin_amdgcn_s_sleep(1);
          w0 = al(sp); w1 = al(sp+1); w2 = al(sp+2); w3 = al(sp+3);
        }
        pk = (uint4){ packhl(__uint_as_float(w0)), packhl(__uint_as_float(w1)),
                      packhl(__uint_as_float(w2)), packhl(__uint_as_float(w3)) };
      } else {
        pk = (uint4){0u, 0u, 0u, 0u};     // s0 = 0
      }
      *((uint4*)(act + row*256 + ((c16 ^ (row & 7)) << 2))) = pk;
    }
    mlp_core(act, wFLu, ubs, ubl, 4, 3, false, tid);
    for (int i = tid; i < 16384; i += 512) usL[i] = act[i];   // verbatim copy

    // ---- v-phase: 4 tiles: enc -> w-MLP -> tanh(+us) -> v-MLP -> e
    for (int k = 0; k < 4; ++k) {
      long m0t = (long)(bid + 256*k) * 64;
      __syncthreads();                    // usL copy done / act free
      for (int i = tid; i < 4096; i += 512) {
        int row = i >> 6, c16 = i & 63;
        long m = m0t + row;
        uint4 pk = *(const uint4*)(henc + HSTR + m*256 + c16*4);
        *((uint4*)(act + row*256 + ((c16 ^ (row & 7)) << 2))) = pk;
      }
      mlp_core(act, wFLw, wbs, wbl, 4, 3, false, tid);   // whs tile (linear out)
      for (int i = tid; i < 16384; i += 512) {
        u32 a = act[i], u = usL[i];
        act[i] = packhl(tanhf(unpackhl(a) + unpackhl(u)));
      }
      mlp_core(act, wFLv, vbs, vbs, 7, 7, true, tid);    // 7 relu layers
      // e-dot: 8 threads per row (32 cols each)
      {
        int r2 = tid >> 3, q = tid & 7;
        float p = 0.f;
        #pragma unroll 8
        for (int j = 0; j < 32; ++j) {
          int n = q*32 + j;
          u32 w = act[r2*256 + (((n >> 2) ^ (r2 & 7)) << 2) + (n & 3)];
          p += unpackhl(w) * vWl[n];
        }
        p += __shfl_xor(p, 1, 64);
        p += __shfl_xor(p, 2, 64);
        p += __shfl_xor(p, 4, 64);
        if (q == 0)
          as_(eS + (size_t)s*65536 + m0t + r2, __float_as_uint(p + vbl[0]) | 1u);
      }
    }

    // ---- attn (blocks 64..191): row b = bid-64
    if (bid >= 64 && bid < 192) {
      int b = bid - 64;
      __syncthreads();                    // reclaim act
      float* asx = (float*)act;           // [512] weights + [512] partials
      const u32* ep0 = eS + (size_t)s*65536 + b;
      u32 w0;
      for (;;) {
        w0 = al(ep0 + (size_t)tid*128);
        if (w0) break;
        __builtin_amdgcn_s_sleep(1);
      }
      float v0 = __uint_as_float(w0);
      const int lane = tid & 63, wv = tid >> 6;
      float m = v0;
      #pragma unroll
      for (int o = 32; o; o >>= 1) m = fmaxf(m, __shfl_xor(m, o, 64));
      if (!lane) red[wv] = m;
      __syncthreads();
      m = fmaxf(fmaxf(fmaxf(red[0], red[1]), fmaxf(red[2], red[3])),
                fmaxf(fmaxf(red[4], red[5]), fmaxf(red[6], red[7])));
      float x0 = expf(v0 - m);
      float sm = x0;
      #pragma unroll
      for (int o = 32; o; o >>= 1) sm += __shfl_xor(sm, o, 64);
      if (!lane) red2[wv] = sm;
      __syncthreads();
      float inv = 1.f / (red2[0] + red2[1] + red2[2] + red2[3]
                       + red2[4] + red2[5] + red2[6] + red2[7]);
      asx[tid] = x0 * inv;
      __syncthreads();
      // ctx: 2 threads per unit, each sums half the t-range
      int unit = tid & 255, hf = tid >> 8;
      float accv = 0.f;
      const u32* hp = henc + HSTR + (size_t)b*256 + unit;
      #pragma unroll 8
      for (int t = hf*256; t < hf*256 + 256; ++t)
        accv += asx[t] * unpackhl(hp[(size_t)t*HSTR]);
      float* part = asx + 512;
      part[tid] = accv;
      __syncthreads();
      if (hf == 0)
        as_(ctxS + (size_t)s*32768 + b*256 + unit,
            __float_as_uint(accv + part[256 + unit]) | 1u);
    }

    // ---- cell + outproj (blocks 224..255): rows 4c..4c+3
    if (bid >= 224) {
      int c = bid - 224, b0r = c*4;
      __syncthreads();                    // reclaim act
      float* xt = (float*)act;            // [4][520]
      const int u = tid & 255, kh = tid >> 8;
      if (kh == 0) {
        const u32* cp = ctxS + (size_t)s*32768 + (size_t)b0r*256 + u;
        u32 w0, w1, w2, w3;
        for (;;) {
          w0 = al(cp); w1 = al(cp + 256); w2 = al(cp + 512); w3 = al(cp + 768);
          if (w0 && w1 && w2 && w3) break;
          __builtin_amdgcn_s_sleep(1);
        }
        xt[0*520 + u] = __uint_as_float(w0);
        xt[1*520 + u] = __uint_as_float(w1);
        xt[2*520 + u] = __uint_as_float(w2);
        xt[3*520 + u] = __uint_as_float(w3);
        #pragma unroll
        for (int bb = 0; bb < 4; ++bb) xt[bb*520 + 256 + u] = sprev[bb];
      }
      __syncthreads();
      float ai[4], ag[4], ao[4];
      #pragma unroll
      for (int bb = 0; bb < 4; ++bb) { ai[bb]=0.f; ag[bb]=0.f; ao[bb]=0.f; }
      #pragma unroll 4
      for (int k = kh*256; k < kh*256 + 256; ++k) {
        float wi = dWt[k*768 + u];
        float wg = dWt[k*768 + 256 + u];
        float wo = dWt[k*768 + 512 + u];
        #pragma unroll
        for (int bb = 0; bb < 4; ++bb) {
          float xv = xt[bb*520 + k];
          ai[bb] += xv*wi; ag[bb] += xv*wg; ao[bb] += xv*wo;
        }
      }
      float* pr = xt + 4*520;             // partials [3][4][256]
      if (kh) {
        #pragma unroll
        for (int bb = 0; bb < 4; ++bb) {
          pr[(0*4 + bb)*256 + u] = ai[bb];
          pr[(1*4 + bb)*256 + u] = ag[bb];
          pr[(2*4 + bb)*256 + u] = ao[bb];
        }
      }
      __syncthreads();
      float* sn = pr + 3*4*256;           // [4][256]
      if (!kh) {
        float bi = dbih[u]       + dbhh[u];
        float bg = dbih[512 + u] + dbhh[512 + u];
        float bo = dbih[768 + u] + dbhh[768 + u];
        #pragma unroll
        for (int bb = 0; bb < 4; ++bb) {
          float a1 = ai[bb] + pr[(0*4 + bb)*256 + u];
          float g1 = ag[bb] + pr[(1*4 + bb)*256 + u];
          float o1 = ao[bb] + pr[(2*4 + bb)*256 + u];
          float cn = sigm(a1 + bi) * tanhf(g1 + bg);
          float hn = sigm(o1 + bo) * tanhf(cn);
          as_(sS + (size_t)(s+1)*32768 + (size_t)(b0r + bb)*256 + u,
              __float_as_uint(hn) | 1u);
          sprev[bb] = hn;
          sn[bb*256 + u] = hn;
        }
      }
      __syncthreads();
      if (tid < 256) {
        int d = tid & 63, rr = tid >> 6;
        float a2 = ob[d];
        #pragma unroll 4
        for (int k = 0; k < 256; ++k) a2 += sn[rr*256 + k] * oW[k*64 + d];
        outc[((size_t)(b0r + rr)*OL_ + s)*64 + d] = a2;
      }
    }
  }
}

// ---------------------------------------------------------------------------
extern "C" void kernel_launch(void* const* d_in, const int* in_sizes, int n_in,
                              void* d_out, int out_size, void* d_ws, size_t ws_size,
                              hipStream_t stream)
{
  (void)in_sizes; (void)n_in;
  const float* x    = (const float*)d_in[0];
  const float* inW  = (const float*)d_in[1];
  const float* inb  = (const float*)d_in[2];
  const float* eWih = (const float*)d_in[3];
  const float* eWhh = (const float*)d_in[4];
  const float* ebih = (const float*)d_in[5];
  const float* ebhh = (const float*)d_in[6];
  const float* dWih = (const float*)d_in[7];
  const float* dbih = (const float*)d_in[9];
  const float* dbhh = (const float*)d_in[10];
  const float* wWs  = (const float*)d_in[11];
  const float* wbs  = (const float*)d_in[12];
  const float* wWl  = (const float*)d_in[13];
  const float* wbl  = (const float*)d_in[14];
  const float* uWs  = (const float*)d_in[15];
  const float* ubs  = (const float*)d_in[16];
  const float* uWl  = (const float*)d_in[17];
  const float* ubl  = (const float*)d_in[18];
  const float* vWs  = (const float*)d_in[19];
  const float* vbs  = (const float*)d_in[20];
  const float* vWl  = (const float*)d_in[21];
  const float* vbl  = (const float*)d_in[22];
  const float* oW   = (const float*)d_in[23];
  const float* ob   = (const float*)d_in[24];
  float* out = (float*)d_out;

  hipFuncSetAttribute((const void*)k_dec_all, hipFuncAttributeMaxDynamicSharedMemorySize, 131072);

  const size_t hsz = (size_t)(T_+1) * HSTR;     // u32 per chunk
  const size_t avail = ws_size / 4;
  auto needf = [&](int nc) -> size_t {
    return (size_t)nc*hsz
         + 1081344ull   /* eS + ctxS + sS scratch */
         + 1770496ull   /* preps */
         + 4096;
  };
  int NC = (needf(2) <= avail) ? 2 : 1;
  if (needf(NC) > avail) { hipMemsetAsync(d_out, 0, (size_t)out_size*4, stream); return; }

  float* wsf = (float*)d_ws;
  size_t o = 0;
  u32* henc = (u32*)(wsf + o);  o += (size_t)NC*hsz;
  u32* eS   = (u32*)(wsf + o);  o += 524288;       // scratch block start
  u32* ctxS = (u32*)(wsf + o);  o += 262144;
  u32* sS   = (u32*)(wsf + o);  o += 294912;       // scratch block end
  float* WpT = wsf + o;  o += 65536;
  float* bp  = wsf + o;  o += 1024;
  float* dWt = wsf + o;  o += 393216;
  u16* whhFL = (u16*)(wsf + o);  o += 262144;
  u16* wpFL  = (u16*)(wsf + o);  o += 65536;
  u16* mlpFL = (u16*)(wsf + o);                    // 983040 float-units

  const size_t scratchBytes = (524288ull + 262144 + 294912) * 4;

  // ---- weight preps (chunk-invariant)
  k_wpt<<<256, 256, 0, stream>>>(inW, eWih, WpT);
  k_bp <<<4,   256, 0, stream>>>(inb, eWih, ebih, ebhh, bp);
  k_dwt<<<1536,256, 0, stream>>>(dWih, dWt);
  k_whhfl<<<1024,256,0,stream>>>(eWhh, whhFL);
  k_wpfl <<<256, 256,0,stream>>>(WpT, wpFL);
  k_wall <<<dim3(256,15), 256, 0, stream>>>(wWs, wWl, uWs, uWl, vWs, mlpFL);

  for (int c0 = 0; c0 < B_; c0 += CBv*NC) {
    hipMemsetAsync(henc, 0, (size_t)NC*hsz*4, stream);   // data-as-flag: clean

    // concurrent chunk encoders
    k_enc<<<dim3(CBv/16, 8, NC), 256, 0, stream>>>(
        x + (size_t)c0*T_*DIN_, whhFL, wpFL, bp, henc);

    for (int z = 0; z < NC; ++z) {
      hipMemsetAsync(eS, 0, scratchBytes, stream);       // step-flags clean
      k_dec_all<<<256, 512, 131072, stream>>>(
          henc + (size_t)z*hsz, mlpFL,
          wbs, wbl, ubs, ubl, vbs, vWl, vbl,
          dWt, dbih, dbhh, oW, ob,
          eS, ctxS, sS,
          out + (size_t)(c0 + z*CBv)*OL_*DOUT_);
    }
  }
}

// Round 13
// 18190.758 us; speedup vs baseline: 1.1772x; 1.1772x over previous
//
#include <hip/hip_runtime.h>
#include <math.h>

#define B_    512
#define T_    512
#define H_    256
#define DIN_  64
#define OL_   8
#define DOUT_ 64

#define CBv   128
#define HSTR  32768          // CBv*256 u32 per henc slot

typedef unsigned short u16;
typedef unsigned int u32;
typedef unsigned long long ull;
typedef __attribute__((ext_vector_type(8))) short short8;   // 8 bf16 (MFMA A/B frag)
typedef __attribute__((ext_vector_type(4))) float f32x4;    // MFMA C/D frag (16x16)

static __device__ __forceinline__ float sigm(float x){ return 1.0f/(1.0f + expf(-x)); }
static __device__ __forceinline__ float bf2f(u16 h){
  u32 u = ((u32)h) << 16; float f; __builtin_memcpy(&f, &u, 4); return f;
}
static __device__ __forceinline__ u16 f2bf(float f){        // RNE
  u32 u; __builtin_memcpy(&u, &f, 4);
  u = (u + 0x7fffu + ((u >> 16) & 1u)) >> 16;
  return (u16)u;
}
static __device__ __forceinline__ u32 packhl(float f){      // hi<<16 | lo
  u16 h = f2bf(f);
  u16 lo = f2bf(f - bf2f(h));
  return ((u32)h << 16) | (u32)lo;
}
static __device__ __forceinline__ float unpackhl(u32 w){
  return bf2f((u16)(w >> 16)) + bf2f((u16)(w & 0xffff));
}
static __device__ __forceinline__ u32 al(const u32* p){
  return __hip_atomic_load(p, __ATOMIC_RELAXED, __HIP_MEMORY_SCOPE_AGENT);
}
static __device__ __forceinline__ void as_(u32* p, u32 v){
  __hip_atomic_store(p, v, __ATOMIC_RELAXED, __HIP_MEMORY_SCOPE_AGENT);
}

// ---------------------------------------------------------------------------
// Weight preps (unchanged, proven)
// ---------------------------------------------------------------------------
__global__ void k_wpt(const float* __restrict__ inW, const float* __restrict__ Wih,
                      float* __restrict__ WpT)
{
  int gid = blockIdx.x * 256 + threadIdx.x;   // 65536
  int c = gid >> 6, d = gid & 63;
  const float* wr = Wih + c * H_;
  const float* ir = inW + d * H_;
  float acc = 0.f;
  #pragma unroll 4
  for (int e = 0; e < H_; e += 4) {
    float4 av = *(const float4*)(ir + e);
    float4 bv = *(const float4*)(wr + e);
    acc += av.x*bv.x + av.y*bv.y + av.z*bv.z + av.w*bv.w;
  }
  WpT[c*64 + d] = acc;
}

__global__ void k_bp(const float* __restrict__ inb, const float* __restrict__ Wih,
                     const float* __restrict__ bih, const float* __restrict__ bhh,
                     float* __restrict__ bp)
{
  int c = blockIdx.x * 256 + threadIdx.x;   // 1024
  const float* wr = Wih + c * H_;
  float acc = bih[c] + bhh[c];
  for (int e = 0; e < H_; ++e) acc += inb[e] * wr[e];
  bp[c] = acc;
}

__global__ void k_dwt(const float* __restrict__ dWih, float* __restrict__ dWt)
{
  int gid = blockIdx.x * 256 + threadIdx.x;   // 393216
  int j = gid >> 9, k = gid & 511;
  int row = (j < 256) ? j : (j + 256);
  dWt[k*768 + j] = dWih[row*512 + k];
}

__global__ void k_wall(const float* __restrict__ wWs, const float* __restrict__ wWl,
                       const float* __restrict__ uWs, const float* __restrict__ uWl,
                       const float* __restrict__ vWs, u16* __restrict__ outb)
{
  int lyr = blockIdx.y;
  const float* W = (lyr < 3)  ? wWs + lyr*65536
                 : (lyr == 3) ? wWl
                 : (lyr < 7)  ? uWs + (lyr-4)*65536
                 : (lyr == 7) ? uWl
                 :              vWs + (lyr-8)*65536;
  u16* out = outb + (size_t)lyr*131072;
  int gid = blockIdx.x * 256 + threadIdx.x;   // 65536
  int k = gid & 255, n = gid >> 8;
  float v = W[k*256 + n];
  int s = k >> 5, j = k & 7;
  int lane = (((k >> 3) & 3) << 4) | (n & 15);
  int fl = ((s*16) + (n >> 4))*512 + lane*8 + j;
  u16 h = f2bf(v);
  out[fl] = h;
  out[65536 + fl] = f2bf(v - bf2f(h));
}

__global__ void k_whhfl(const float* __restrict__ Whh, u16* __restrict__ out)
{
  int gid = blockIdx.x * 256 + threadIdx.x;   // 262144
  int j = gid & 7, l = (gid >> 3) & 63, ctg = (gid >> 9) & 63, s = gid >> 15;
  int k = s*32 + (l >> 4)*8 + j;
  int wv = ctg >> 2, g = ctg & 3;
  int row = g*256 + wv*16 + (l & 15);
  float v = Whh[row*256 + k];
  int fl = (s*64 + ctg)*512 + l*8 + j;
  u16 h = f2bf(v);
  out[fl] = h;
  out[262144 + fl] = f2bf(v - bf2f(h));
}

__global__ void k_wpfl(const float* __restrict__ WpT, u16* __restrict__ out)
{
  int gid = blockIdx.x * 256 + threadIdx.x;   // 65536
  int j = gid & 7, l = (gid >> 3) & 63, ctg = (gid >> 9) & 63, s = gid >> 15;
  int k = s*32 + (l >> 4)*8 + j;              // < 64
  int wv = ctg >> 2, g = ctg & 3;
  int row = g*256 + wv*16 + (l & 15);
  float v = WpT[row*64 + k];
  int fl = (s*64 + ctg)*512 + l*8 + j;
  u16 h = f2bf(v);
  out[fl] = h;
  out[65536 + fl] = f2bf(v - bf2f(h));
}

// ---------------------------------------------------------------------------
// Clustered persistent encoder, DATA-AS-FLAG (r9, proven; unchanged).
// grid = (CBv/16, 8, NC).
// ---------------------------------------------------------------------------
__global__ __launch_bounds__(256,1) void k_enc(
    const float* __restrict__ x, const u16* __restrict__ whhFL,
    const u16* __restrict__ wpFL, const float* __restrict__ bp,
    u32* __restrict__ henc)
{
  __shared__ float G[2][16][32][4];
  const int tid = threadIdx.x, l = tid & 63, wv = tid >> 6;
  const int lr = l & 15, lk = l >> 4;
  const int rg = blockIdx.x, bg = blockIdx.y, z = blockIdx.z;
  const int ug2 = wv >> 1;
  const int g0 = (wv & 1) * 2;
  const int u16g = bg*2 + ug2;

  short8 whH[8][2], whL[8][2], wpH[2][2], wpL[2][2];
  #pragma unroll
  for (int s = 0; s < 8; ++s)
    #pragma unroll
    for (int c = 0; c < 2; ++c) {
      int ctg = u16g*4 + g0 + c;
      whH[s][c] = *(const short8*)(whhFL + ((size_t)(s*64 + ctg))*512 + l*8);
      whL[s][c] = *(const short8*)(whhFL + 262144 + ((size_t)(s*64 + ctg))*512 + l*8);
    }
  #pragma unroll
  for (int s = 0; s < 2; ++s)
    #pragma unroll
    for (int c = 0; c < 2; ++c) {
      int ctg = u16g*4 + g0 + c;
      wpH[s][c] = *(const short8*)(wpFL + ((size_t)(s*64 + ctg))*512 + l*8);
      wpL[s][c] = *(const short8*)(wpFL + 65536 + ((size_t)(s*64 + ctg))*512 + l*8);
    }
  const int ul = tid & 31, er0 = tid >> 5;
  float bb[4];
  #pragma unroll
  for (int g = 0; g < 4; ++g) bb[g] = bp[g*256 + bg*32 + ul];
  float cs[2] = {0.f, 0.f};

  u32* hz = henc + (size_t)z * (size_t)(T_+1) * HSTR;
  const float* xrow = x + ((size_t)(z*CBv + rg*16 + lr)*T_)*DIN_ + lk*8;

  for (int t = 0; t < T_; ++t) {
    float4 xv0 = *(const float4*)(xrow);
    float4 xv1 = *(const float4*)(xrow + 4);
    float4 xv2 = *(const float4*)(xrow + 32);
    float4 xv3 = *(const float4*)(xrow + 36);
    xrow += DIN_;

    const ull* hb = (const ull*)(hz + (size_t)t*HSTR + (size_t)(rg*16 + lr)*256);
    ull hq[8][4];
    #pragma unroll
    for (int s = 0; s < 8; ++s)
      #pragma unroll
      for (int q = 0; q < 4; ++q)
        hq[s][q] = __hip_atomic_load(hb + s*16 + lk*4 + q,
                                     __ATOMIC_RELAXED, __HIP_MEMORY_SCOPE_AGENT);
    if (t) {
      for (;;) {
        bool ok = true;
        #pragma unroll
        for (int s = 0; s < 8; ++s)
          #pragma unroll
          for (int q = 0; q < 4; ++q) {
            u32 a = (u32)hq[s][q], b = (u32)(hq[s][q] >> 32);
            ok = ok && (a != 0u) && (b != 0u);
          }
        if (__all(ok)) break;
        __builtin_amdgcn_s_sleep(1);
        #pragma unroll
        for (int s = 0; s < 8; ++s)
          #pragma unroll
          for (int q = 0; q < 4; ++q)
            hq[s][q] = __hip_atomic_load(hb + s*16 + lk*4 + q,
                                         __ATOMIC_RELAXED, __HIP_MEMORY_SCOPE_AGENT);
      }
    }

    f32x4 acc[2];
    acc[0] = (f32x4){0.f,0.f,0.f,0.f};
    acc[1] = (f32x4){0.f,0.f,0.f,0.f};

    #pragma unroll
    for (int s = 0; s < 2; ++s) {
      float vv[8];
      if (s == 0) { vv[0]=xv0.x;vv[1]=xv0.y;vv[2]=xv0.z;vv[3]=xv0.w;vv[4]=xv1.x;vv[5]=xv1.y;vv[6]=xv1.z;vv[7]=xv1.w; }
      else        { vv[0]=xv2.x;vv[1]=xv2.y;vv[2]=xv2.z;vv[3]=xv2.w;vv[4]=xv3.x;vv[5]=xv3.y;vv[6]=xv3.z;vv[7]=xv3.w; }
      short8 ah, al2;
      #pragma unroll
      for (int j = 0; j < 8; ++j) {
        u16 h = f2bf(vv[j]);
        ah[j] = (short)h;
        al2[j] = (short)f2bf(vv[j] - bf2f(h));
      }
      #pragma unroll
      for (int c = 0; c < 2; ++c) {
        acc[c] = __builtin_amdgcn_mfma_f32_16x16x32_bf16(ah,  wpH[s][c], acc[c], 0,0,0);
        acc[c] = __builtin_amdgcn_mfma_f32_16x16x32_bf16(al2, wpH[s][c], acc[c], 0,0,0);
        acc[c] = __builtin_amdgcn_mfma_f32_16x16x32_bf16(ah,  wpL[s][c], acc[c], 0,0,0);
      }
    }
    #pragma unroll
    for (int s = 0; s < 8; ++s) {
      short8 ah, al2;
      #pragma unroll
      for (int q = 0; q < 4; ++q) {
        u32 w0 = (u32)hq[s][q], w1 = (u32)(hq[s][q] >> 32);
        ah[q*2]   = (short)(w0 >> 16); al2[q*2]   = (short)(w0 & 0xffff);
        ah[q*2+1] = (short)(w1 >> 16); al2[q*2+1] = (short)(w1 & 0xffff);
      }
      #pragma unroll
      for (int c = 0; c < 2; ++c) {
        acc[c] = __builtin_amdgcn_mfma_f32_16x16x32_bf16(ah,  whH[s][c], acc[c], 0,0,0);
        acc[c] = __builtin_amdgcn_mfma_f32_16x16x32_bf16(al2, whH[s][c], acc[c], 0,0,0);
        acc[c] = __builtin_amdgcn_mfma_f32_16x16x32_bf16(ah,  whL[s][c], acc[c], 0,0,0);
      }
    }

    const int p = t & 1;
    #pragma unroll
    for (int c = 0; c < 2; ++c)
      #pragma unroll
      for (int j = 0; j < 4; ++j)
        G[p][lk*4 + j][ug2*16 + lr][g0 + c] = acc[c][j];
    __syncthreads();

    #pragma unroll
    for (int pp = 0; pp < 2; ++pp) {
      int row = er0 + pp*8;
      float4 gq = *(const float4*)&G[p][row][ul][0];
      float gi = gq.x + bb[0], gf = gq.y + bb[1];
      float gg = gq.z + bb[2], go = gq.w + bb[3];
      float cn = sigm(gf)*cs[pp] + sigm(gi)*tanhf(gg);
      float hn = sigm(go)*tanhf(cn);
      cs[pp] = cn;
      as_(hz + (size_t)(t+1)*HSTR + (size_t)(rg*16 + row)*256 + bg*32 + ul,
          packhl(hn) | 1u);
    }
  }
}

// ---------------------------------------------------------------------------
// MLP layer-loop core, 512 thr = 8 waves (2 row-groups x 4 col-groups).
// B triple-buffered: prefetch slab s+2 while computing s (covers L2/IC latency
// that a 1-deep buffer cannot: per-slab MFMA ~230 cyc < ~500-900 cyc load RT).
// act: [64][256] u32 packhl, chunk-swizzled. Leaves final activations in act.
// ---------------------------------------------------------------------------
static __device__ __forceinline__ void mlp_core(
    u32* act, const u16* wFL, const float* bs, const float* bl,
    int L, int nbs, bool lastRelu, int tid)
{
  const int l = tid & 63, w = tid >> 6;
  const int rg = w >> 2, cg = w & 3;
  const int lr = l & 15, lk = l >> 4;
  const int wrow = rg*32;
  f32x4 acc[2][4];
  for (int lyr = 0; lyr < L; ++lyr) {
    __syncthreads();
    const u16* wb = wFL + (size_t)lyr*131072;
    #pragma unroll
    for (int rt = 0; rt < 2; ++rt)
      #pragma unroll
      for (int ct = 0; ct < 4; ++ct) acc[rt][ct] = (f32x4){0.f,0.f,0.f,0.f};

    short8 bh[3][4], blo[3][4];
    #pragma unroll
    for (int pre = 0; pre < 2; ++pre)
      #pragma unroll
      for (int ct = 0; ct < 4; ++ct) {
        const u16* bfp = wb + ((size_t)(pre*16 + cg*4 + ct))*512 + l*8;
        bh[pre][ct]  = *(const short8*)bfp;
        blo[pre][ct] = *(const short8*)(bfp + 65536);
      }
    #pragma unroll
    for (int s = 0; s < 8; ++s) {
      const int cur = s % 3, nxt = (s + 2) % 3;
      if (s < 6) {
        #pragma unroll
        for (int ct = 0; ct < 4; ++ct) {
          const u16* bfp = wb + ((size_t)((s+2)*16 + cg*4 + ct))*512 + l*8;
          bh[nxt][ct]  = *(const short8*)bfp;
          blo[nxt][ct] = *(const short8*)(bfp + 65536);
        }
      }
      short8 ah[2], al2[2];
      #pragma unroll
      for (int rt = 0; rt < 2; ++rt) {
        int row = wrow + rt*16 + lr;
        int cc = s*8 + lk*2;
        const u32* base = act + row*256;
        uint4 d0 = *(const uint4*)(base + (((cc    ) ^ (row & 7)) << 2));
        uint4 d1 = *(const uint4*)(base + (((cc + 1) ^ (row & 7)) << 2));
        u32 q[8] = {d0.x,d0.y,d0.z,d0.w,d1.x,d1.y,d1.z,d1.w};
        #pragma unroll
        for (int j = 0; j < 8; ++j) {
          ah[rt][j]  = (short)(q[j] >> 16);
          al2[rt][j] = (short)(q[j] & 0xffff);
        }
      }
      #pragma unroll
      for (int ct = 0; ct < 4; ++ct)
        #pragma unroll
        for (int rt = 0; rt < 2; ++rt) {
          acc[rt][ct] = __builtin_amdgcn_mfma_f32_16x16x32_bf16(ah[rt],  bh[cur][ct],  acc[rt][ct], 0,0,0);
          acc[rt][ct] = __builtin_amdgcn_mfma_f32_16x16x32_bf16(al2[rt], bh[cur][ct],  acc[rt][ct], 0,0,0);
          acc[rt][ct] = __builtin_amdgcn_mfma_f32_16x16x32_bf16(ah[rt],  blo[cur][ct], acc[rt][ct], 0,0,0);
        }
    }
    const float* bptr = (lyr < nbs) ? (bs + lyr*256) : bl;
    const bool dorelu = (lyr < L-1) || lastRelu;
    #pragma unroll
    for (int ct = 0; ct < 4; ++ct) {
      float bv = bptr[cg*64 + ct*16 + lr];
      #pragma unroll
      for (int rt = 0; rt < 2; ++rt)
        #pragma unroll
        for (int g = 0; g < 4; ++g) {
          float xv = acc[rt][ct][g] + bv;
          acc[rt][ct][g] = dorelu ? fmaxf(xv, 0.f) : xv;
        }
    }
    __syncthreads();
    #pragma unroll
    for (int ct = 0; ct < 4; ++ct) {
      int n = cg*64 + ct*16 + lr;
      #pragma unroll
      for (int rt = 0; rt < 2; ++rt)
        #pragma unroll
        for (int g = 0; g < 4; ++g) {
          int row = wrow + rt*16 + lk*4 + g;
          act[row*256 + (((n >> 2) ^ (row & 7)) << 2) + (n & 3)] = packhl(acc[rt][ct][g]);
        }
    }
  }
  __syncthreads();
}

// ---------------------------------------------------------------------------
// MEGA decode kernel v3, 512 thr, 128KB LDS (act 64KB + usL 64KB):
//  - whsP != nullptr: whs computed ONCE into whsP; v-stage staging fuses
//    tanh(whsP + usL) (no per-step w-recompute).
//  - whsP == nullptr: fallback to r12's w-recompute path.
//  - u-MLP computed locally per block (its us-half) into usL.
// ---------------------------------------------------------------------------
__global__ __launch_bounds__(512,1) void k_dec_all(
    const u32* __restrict__ henc, const u16* __restrict__ mlpFL,
    const float* __restrict__ wbs, const float* __restrict__ wbl,
    const float* __restrict__ ubs, const float* __restrict__ ubl,
    const float* __restrict__ vbs, const float* __restrict__ vWl,
    const float* __restrict__ vbl,
    const float* __restrict__ dWt, const float* __restrict__ dbih,
    const float* __restrict__ dbhh,
    const float* __restrict__ oW, const float* __restrict__ ob,
    u32* __restrict__ whsP,
    u32* __restrict__ eS, u32* __restrict__ ctxS, u32* __restrict__ sS,
    float* __restrict__ outc)
{
  extern __shared__ u32 act[];            // [16384] act + [16384] usL
  __shared__ float red[8], red2[8];
  const int bid = blockIdx.x, tid = threadIdx.x;
  u32* usL = act + 16384;
  const u16* wFLw = mlpFL;
  const u16* wFLu = mlpFL + 4*131072;
  const u16* wFLv = mlpFL + 8*131072;
  const int half = bid & 1;
  const bool useW = (whsP != nullptr);
  float sprev[4] = {0.f, 0.f, 0.f, 0.f};

  // ======== whs precompute (once): 4 block-local tiles -> whsP ========
  if (useW) {
    for (int k = 0; k < 4; ++k) {
      long m0t = (long)(bid + 256*k) * 64;
      __syncthreads();
      for (int i = tid; i < 4096; i += 512) {
        int row = i >> 6, c16 = i & 63;
        uint4 pk = *(const uint4*)(henc + HSTR + (m0t + row)*256 + c16*4);
        *((uint4*)(act + row*256 + ((c16 ^ (row & 7)) << 2))) = pk;
      }
      mlp_core(act, wFLw, wbs, wbl, 4, 3, false, tid);
      for (int i = tid; i < 4096; i += 512) {
        int row = i >> 6, c16 = i & 63;
        uint4 pk = *((const uint4*)(act + row*256 + ((c16 ^ (row & 7)) << 2)));
        *(uint4*)(whsP + (m0t + row)*256 + c16*4) = pk;
      }
    }
  }

  // ======== decode steps ========
  for (int s = 0; s < OL_; ++s) {
    // ---- u-phase: ALL blocks compute their us-half locally
    __syncthreads();                      // prior-step LDS uses complete
    for (int i = tid; i < 4096; i += 512) {
      int row = i >> 6, c16 = i & 63;
      uint4 pk;
      if (s) {
        const u32* sp = sS + (size_t)s*32768 + (size_t)(half*64 + row)*256 + c16*4;
        u32 w0 = al(sp), w1 = al(sp+1), w2 = al(sp+2), w3 = al(sp+3);
        while (!(w0 && w1 && w2 && w3)) {
          __builtin_amdgcn_s_sleep(1);
          w0 = al(sp); w1 = al(sp+1); w2 = al(sp+2); w3 = al(sp+3);
        }
        pk = (uint4){ packhl(__uint_as_float(w0)), packhl(__uint_as_float(w1)),
                      packhl(__uint_as_float(w2)), packhl(__uint_as_float(w3)) };
      } else {
        pk = (uint4){0u, 0u, 0u, 0u};     // s0 = 0
      }
      *((uint4*)(act + row*256 + ((c16 ^ (row & 7)) << 2))) = pk;
    }
    mlp_core(act, wFLu, ubs, ubl, 4, 3, false, tid);
    for (int i = tid; i < 16384; i += 512) usL[i] = act[i];   // verbatim copy

    // ---- v-phase: 4 tiles
    for (int k = 0; k < 4; ++k) {
      long m0t = (long)(bid + 256*k) * 64;
      __syncthreads();                    // usL copy done / act free
      if (useW) {
        // fused staging: act = packhl(tanh(whsP + usL))
        for (int i = tid; i < 4096; i += 512) {
          int row = i >> 6, c16 = i & 63;
          uint4 pw = *(const uint4*)(whsP + (m0t + row)*256 + c16*4);
          u32* dst = act + row*256 + ((c16 ^ (row & 7)) << 2);
          const u32* uw = usL + row*256 + ((c16 ^ (row & 7)) << 2);
          dst[0] = packhl(tanhf(unpackhl(pw.x) + unpackhl(uw[0])));
          dst[1] = packhl(tanhf(unpackhl(pw.y) + unpackhl(uw[1])));
          dst[2] = packhl(tanhf(unpackhl(pw.z) + unpackhl(uw[2])));
          dst[3] = packhl(tanhf(unpackhl(pw.w) + unpackhl(uw[3])));
        }
      } else {
        for (int i = tid; i < 4096; i += 512) {
          int row = i >> 6, c16 = i & 63;
          uint4 pk = *(const uint4*)(henc + HSTR + (m0t + row)*256 + c16*4);
          *((uint4*)(act + row*256 + ((c16 ^ (row & 7)) << 2))) = pk;
        }
        mlp_core(act, wFLw, wbs, wbl, 4, 3, false, tid);   // whs tile
        for (int i = tid; i < 16384; i += 512) {
          u32 a = act[i], u = usL[i];
          act[i] = packhl(tanhf(unpackhl(a) + unpackhl(u)));
        }
      }
      mlp_core(act, wFLv, vbs, vbs, 7, 7, true, tid);      // 7 relu layers
      // e-dot: 8 threads per row (32 cols each)
      {
        int r2 = tid >> 3, q = tid & 7;
        float p = 0.f;
        #pragma unroll 8
        for (int j = 0; j < 32; ++j) {
          int n = q*32 + j;
          u32 w = act[r2*256 + (((n >> 2) ^ (r2 & 7)) << 2) + (n & 3)];
          p += unpackhl(w) * vWl[n];
        }
        p += __shfl_xor(p, 1, 64);
        p += __shfl_xor(p, 2, 64);
        p += __shfl_xor(p, 4, 64);
        if (q == 0)
          as_(eS + (size_t)s*65536 + m0t + r2, __float_as_uint(p + vbl[0]) | 1u);
      }
    }

    // ---- attn (blocks 64..191): row b = bid-64
    if (bid >= 64 && bid < 192) {
      int b = bid - 64;
      __syncthreads();                    // reclaim act
      float* asx = (float*)act;           // [512] weights + [512] partials
      const u32* ep0 = eS + (size_t)s*65536 + b;
      u32 w0;
      for (;;) {
        w0 = al(ep0 + (size_t)tid*128);
        if (w0) break;
        __builtin_amdgcn_s_sleep(1);
      }
      float v0 = __uint_as_float(w0);
      const int lane = tid & 63, wv = tid >> 6;
      float m = v0;
      #pragma unroll
      for (int o = 32; o; o >>= 1) m = fmaxf(m, __shfl_xor(m, o, 64));
      if (!lane) red[wv] = m;
      __syncthreads();
      m = fmaxf(fmaxf(fmaxf(red[0], red[1]), fmaxf(red[2], red[3])),
                fmaxf(fmaxf(red[4], red[5]), fmaxf(red[6], red[7])));
      float x0 = expf(v0 - m);
      float sm = x0;
      #pragma unroll
      for (int o = 32; o; o >>= 1) sm += __shfl_xor(sm, o, 64);
      if (!lane) red2[wv] = sm;
      __syncthreads();
      float inv = 1.f / (red2[0] + red2[1] + red2[2] + red2[3]
                       + red2[4] + red2[5] + red2[6] + red2[7]);
      asx[tid] = x0 * inv;
      __syncthreads();
      // ctx: 2 threads per unit, each sums half the t-range
      int unit = tid & 255, hf = tid >> 8;
      float accv = 0.f;
      const u32* hp = henc + HSTR + (size_t)b*256 + unit;
      #pragma unroll 8
      for (int t = hf*256; t < hf*256 + 256; ++t)
        accv += asx[t] * unpackhl(hp[(size_t)t*HSTR]);
      float* part = asx + 512;
      part[tid] = accv;
      __syncthreads();
      if (hf == 0)
        as_(ctxS + (size_t)s*32768 + b*256 + unit,
            __float_as_uint(accv + part[256 + unit]) | 1u);
    }

    // ---- cell + outproj (blocks 224..255): rows 4c..4c+3
    if (bid >= 224) {
      int c = bid - 224, b0r = c*4;
      __syncthreads();                    // reclaim act
      float* xt = (float*)act;            // [4][520]
      const int u = tid & 255, kh = tid >> 8;
      if (kh == 0) {
        const u32* cp = ctxS + (size_t)s*32768 + (size_t)b0r*256 + u;
        u32 w0, w1, w2, w3;
        for (;;) {
          w0 = al(cp); w1 = al(cp + 256); w2 = al(cp + 512); w3 = al(cp + 768);
          if (w0 && w1 && w2 && w3) break;
          __builtin_amdgcn_s_sleep(1);
        }
        xt[0*520 + u] = __uint_as_float(w0);
        xt[1*520 + u] = __uint_as_float(w1);
        xt[2*520 + u] = __uint_as_float(w2);
        xt[3*520 + u] = __uint_as_float(w3);
        #pragma unroll
        for (int bb = 0; bb < 4; ++bb) xt[bb*520 + 256 + u] = sprev[bb];
      }
      __syncthreads();
      float ai[4], ag[4], ao[4];
      #pragma unroll
      for (int bb = 0; bb < 4; ++bb) { ai[bb]=0.f; ag[bb]=0.f; ao[bb]=0.f; }
      #pragma unroll 4
      for (int k = kh*256; k < kh*256 + 256; ++k) {
        float wi = dWt[k*768 + u];
        float wg = dWt[k*768 + 256 + u];
        float wo = dWt[k*768 + 512 + u];
        #pragma unroll
        for (int bb = 0; bb < 4; ++bb) {
          float xv = xt[bb*520 + k];
          ai[bb] += xv*wi; ag[bb] += xv*wg; ao[bb] += xv*wo;
        }
      }
      float* pr = xt + 4*520;             // partials [3][4][256]
      if (kh) {
        #pragma unroll
        for (int bb = 0; bb < 4; ++bb) {
          pr[(0*4 + bb)*256 + u] = ai[bb];
          pr[(1*4 + bb)*256 + u] = ag[bb];
          pr[(2*4 + bb)*256 + u] = ao[bb];
        }
      }
      __syncthreads();
      float* sn = pr + 3*4*256;           // [4][256]
      if (!kh) {
        float bi = dbih[u]       + dbhh[u];
        float bg = dbih[512 + u] + dbhh[512 + u];
        float bo = dbih[768 + u] + dbhh[768 + u];
        #pragma unroll
        for (int bb = 0; bb < 4; ++bb) {
          float a1 = ai[bb] + pr[(0*4 + bb)*256 + u];
          float g1 = ag[bb] + pr[(1*4 + bb)*256 + u];
          float o1 = ao[bb] + pr[(2*4 + bb)*256 + u];
          float cn = sigm(a1 + bi) * tanhf(g1 + bg);
          float hn = sigm(o1 + bo) * tanhf(cn);
          as_(sS + (size_t)(s+1)*32768 + (size_t)(b0r + bb)*256 + u,
              __float_as_uint(hn) | 1u);
          sprev[bb] = hn;
          sn[bb*256 + u] = hn;
        }
      }
      __syncthreads();
      if (tid < 256) {
        int d = tid & 63, rr = tid >> 6;
        float a2 = ob[d];
        #pragma unroll 4
        for (int k = 0; k < 256; ++k) a2 += sn[rr*256 + k] * oW[k*64 + d];
        outc[((size_t)(b0r + rr)*OL_ + s)*64 + d] = a2;
      }
    }
  }
}

// ---------------------------------------------------------------------------
extern "C" void kernel_launch(void* const* d_in, const int* in_sizes, int n_in,
                              void* d_out, int out_size, void* d_ws, size_t ws_size,
                              hipStream_t stream)
{
  (void)in_sizes; (void)n_in;
  const float* x    = (const float*)d_in[0];
  const float* inW  = (const float*)d_in[1];
  const float* inb  = (const float*)d_in[2];
  const float* eWih = (const float*)d_in[3];
  const float* eWhh = (const float*)d_in[4];
  const float* ebih = (const float*)d_in[5];
  const float* ebhh = (const float*)d_in[6];
  const float* dWih = (const float*)d_in[7];
  const float* dbih = (const float*)d_in[9];
  const float* dbhh = (const float*)d_in[10];
  const float* wWs  = (const float*)d_in[11];
  const float* wbs  = (const float*)d_in[12];
  const float* wWl  = (const float*)d_in[13];
  const float* wbl  = (const float*)d_in[14];
  const float* uWs  = (const float*)d_in[15];
  const float* ubs  = (const float*)d_in[16];
  const float* uWl  = (const float*)d_in[17];
  const float* ubl  = (const float*)d_in[18];
  const float* vWs  = (const float*)d_in[19];
  const float* vbs  = (const float*)d_in[20];
  const float* vWl  = (const float*)d_in[21];
  const float* vbl  = (const float*)d_in[22];
  const float* oW   = (const float*)d_in[23];
  const float* ob   = (const float*)d_in[24];
  float* out = (float*)d_out;

  hipFuncSetAttribute((const void*)k_dec_all, hipFuncAttributeMaxDynamicSharedMemorySize, 131072);

  const size_t hsz = (size_t)(T_+1) * HSTR;     // u32 per chunk
  const size_t avail = ws_size / 4;
  const size_t scratchU = 524288ull + 262144 + 294912;   // eS + ctxS + sS
  const size_t prepsU = 1770496ull;
  auto needf = [&](int nc, int usewhs) -> size_t {
    return (size_t)nc*hsz + (usewhs ? 16777216ull : 0ull) + scratchU + prepsU + 4096;
  };
  int NC = 1, USEW = 0;
  if      (needf(2,1) <= avail) { NC = 2; USEW = 1; }   // 213 MB
  else if (needf(1,1) <= avail) { NC = 1; USEW = 1; }   // 150 MB
  else if (needf(1,0) <= avail) { NC = 1; USEW = 0; }   // 133 MB
  else { hipMemsetAsync(d_out, 0, (size_t)out_size*4, stream); return; }

  float* wsf = (float*)d_ws;
  size_t o = 0;
  u32* henc = (u32*)(wsf + o);  o += (size_t)NC*hsz;
  u32* whsP = nullptr;
  if (USEW) { whsP = (u32*)(wsf + o);  o += 16777216; }
  u32* eS   = (u32*)(wsf + o);  o += 524288;       // scratch block start
  u32* ctxS = (u32*)(wsf + o);  o += 262144;
  u32* sS   = (u32*)(wsf + o);  o += 294912;       // scratch block end
  float* WpT = wsf + o;  o += 65536;
  float* bp  = wsf + o;  o += 1024;
  float* dWt = wsf + o;  o += 393216;
  u16* whhFL = (u16*)(wsf + o);  o += 262144;
  u16* wpFL  = (u16*)(wsf + o);  o += 65536;
  u16* mlpFL = (u16*)(wsf + o);                    // 983040 float-units

  const size_t scratchBytes = scratchU * 4;

  // ---- weight preps (chunk-invariant)
  k_wpt<<<256, 256, 0, stream>>>(inW, eWih, WpT);
  k_bp <<<4,   256, 0, stream>>>(inb, eWih, ebih, ebhh, bp);
  k_dwt<<<1536,256, 0, stream>>>(dWih, dWt);
  k_whhfl<<<1024,256,0,stream>>>(eWhh, whhFL);
  k_wpfl <<<256, 256,0,stream>>>(WpT, wpFL);
  k_wall <<<dim3(256,15), 256, 0, stream>>>(wWs, wWl, uWs, uWl, vWs, mlpFL);

  for (int c0 = 0; c0 < B_; c0 += CBv*NC) {
    hipMemsetAsync(henc, 0, (size_t)NC*hsz*4, stream);   // data-as-flag: clean

    // concurrent chunk encoders
    k_enc<<<dim3(CBv/16, 8, NC), 256, 0, stream>>>(
        x + (size_t)c0*T_*DIN_, whhFL, wpFL, bp, henc);

    for (int z = 0; z < NC; ++z) {
      hipMemsetAsync(eS, 0, scratchBytes, stream);       // step-flags clean
      k_dec_all<<<256, 512, 131072, stream>>>(
          henc + (size_t)z*hsz, mlpFL,
          wbs, wbl, ubs, ubl, vbs, vWl, vbl,
          dWt, dbih, dbhh, oW, ob,
          whsP, eS, ctxS, sS,
          out + (size_t)(c0 + z*CBv)*OL_*DOUT_);
    }
  }
}

// Round 14
// 16635.922 us; speedup vs baseline: 1.2873x; 1.0935x over previous
//
#include <hip/hip_runtime.h>
#include <math.h>

#define B_    512
#define T_    512
#define H_    256
#define DIN_  64
#define OL_   8
#define DOUT_ 64

#define CBv   128
#define HSTR  32768          // CBv*256 u32 per henc slot

typedef unsigned short u16;
typedef unsigned int u32;
typedef unsigned long long ull;
typedef __attribute__((ext_vector_type(8))) short short8;   // 8 bf16 (MFMA A/B frag)
typedef __attribute__((ext_vector_type(4))) float f32x4;    // MFMA C/D frag (16x16)

static __device__ __forceinline__ float sigm(float x){ return 1.0f/(1.0f + expf(-x)); }
static __device__ __forceinline__ float bf2f(u16 h){
  u32 u = ((u32)h) << 16; float f; __builtin_memcpy(&f, &u, 4); return f;
}
static __device__ __forceinline__ u16 f2bf(float f){        // RNE
  u32 u; __builtin_memcpy(&u, &f, 4);
  u = (u + 0x7fffu + ((u >> 16) & 1u)) >> 16;
  return (u16)u;
}
static __device__ __forceinline__ u32 packhl(float f){      // hi<<16 | lo
  u16 h = f2bf(f);
  u16 lo = f2bf(f - bf2f(h));
  return ((u32)h << 16) | (u32)lo;
}
static __device__ __forceinline__ float unpackhl(u32 w){
  return bf2f((u16)(w >> 16)) + bf2f((u16)(w & 0xffff));
}
static __device__ __forceinline__ u32 al(const u32* p){
  return __hip_atomic_load(p, __ATOMIC_RELAXED, __HIP_MEMORY_SCOPE_AGENT);
}
static __device__ __forceinline__ void as_(u32* p, u32 v){
  __hip_atomic_store(p, v, __ATOMIC_RELAXED, __HIP_MEMORY_SCOPE_AGENT);
}

// ---------------------------------------------------------------------------
// Weight preps (unchanged, proven)
// ---------------------------------------------------------------------------
__global__ void k_wpt(const float* __restrict__ inW, const float* __restrict__ Wih,
                      float* __restrict__ WpT)
{
  int gid = blockIdx.x * 256 + threadIdx.x;   // 65536
  int c = gid >> 6, d = gid & 63;
  const float* wr = Wih + c * H_;
  const float* ir = inW + d * H_;
  float acc = 0.f;
  #pragma unroll 4
  for (int e = 0; e < H_; e += 4) {
    float4 av = *(const float4*)(ir + e);
    float4 bv = *(const float4*)(wr + e);
    acc += av.x*bv.x + av.y*bv.y + av.z*bv.z + av.w*bv.w;
  }
  WpT[c*64 + d] = acc;
}

__global__ void k_bp(const float* __restrict__ inb, const float* __restrict__ Wih,
                     const float* __restrict__ bih, const float* __restrict__ bhh,
                     float* __restrict__ bp)
{
  int c = blockIdx.x * 256 + threadIdx.x;   // 1024
  const float* wr = Wih + c * H_;
  float acc = bih[c] + bhh[c];
  for (int e = 0; e < H_; ++e) acc += inb[e] * wr[e];
  bp[c] = acc;
}

__global__ void k_dwt(const float* __restrict__ dWih, float* __restrict__ dWt)
{
  int gid = blockIdx.x * 256 + threadIdx.x;   // 393216
  int j = gid >> 9, k = gid & 511;
  int row = (j < 256) ? j : (j + 256);
  dWt[k*768 + j] = dWih[row*512 + k];
}

__global__ void k_wall(const float* __restrict__ wWs, const float* __restrict__ wWl,
                       const float* __restrict__ uWs, const float* __restrict__ uWl,
                       const float* __restrict__ vWs, u16* __restrict__ outb)
{
  int lyr = blockIdx.y;
  const float* W = (lyr < 3)  ? wWs + lyr*65536
                 : (lyr == 3) ? wWl
                 : (lyr < 7)  ? uWs + (lyr-4)*65536
                 : (lyr == 7) ? uWl
                 :              vWs + (lyr-8)*65536;
  u16* out = outb + (size_t)lyr*131072;
  int gid = blockIdx.x * 256 + threadIdx.x;   // 65536
  int k = gid & 255, n = gid >> 8;
  float v = W[k*256 + n];
  int s = k >> 5, j = k & 7;
  int lane = (((k >> 3) & 3) << 4) | (n & 15);
  int fl = ((s*16) + (n >> 4))*512 + lane*8 + j;
  u16 h = f2bf(v);
  out[fl] = h;
  out[65536 + fl] = f2bf(v - bf2f(h));
}

__global__ void k_whhfl(const float* __restrict__ Whh, u16* __restrict__ out)
{
  int gid = blockIdx.x * 256 + threadIdx.x;   // 262144
  int j = gid & 7, l = (gid >> 3) & 63, ctg = (gid >> 9) & 63, s = gid >> 15;
  int k = s*32 + (l >> 4)*8 + j;
  int wv = ctg >> 2, g = ctg & 3;
  int row = g*256 + wv*16 + (l & 15);
  float v = Whh[row*256 + k];
  int fl = (s*64 + ctg)*512 + l*8 + j;
  u16 h = f2bf(v);
  out[fl] = h;
  out[262144 + fl] = f2bf(v - bf2f(h));
}

__global__ void k_wpfl(const float* __restrict__ WpT, u16* __restrict__ out)
{
  int gid = blockIdx.x * 256 + threadIdx.x;   // 65536
  int j = gid & 7, l = (gid >> 3) & 63, ctg = (gid >> 9) & 63, s = gid >> 15;
  int k = s*32 + (l >> 4)*8 + j;              // < 64
  int wv = ctg >> 2, g = ctg & 3;
  int row = g*256 + wv*16 + (l & 15);
  float v = WpT[row*64 + k];
  int fl = (s*64 + ctg)*512 + l*8 + j;
  u16 h = f2bf(v);
  out[fl] = h;
  out[65536 + fl] = f2bf(v - bf2f(h));
}

// ---------------------------------------------------------------------------
// Clustered persistent encoder, DATA-AS-FLAG (r9, proven; unchanged).
// grid = (CBv/16, 8, NC). All blocks co-resident for any NC <= 4.
// ---------------------------------------------------------------------------
__global__ __launch_bounds__(256,1) void k_enc(
    const float* __restrict__ x, const u16* __restrict__ whhFL,
    const u16* __restrict__ wpFL, const float* __restrict__ bp,
    u32* __restrict__ henc)
{
  __shared__ float G[2][16][32][4];
  const int tid = threadIdx.x, l = tid & 63, wv = tid >> 6;
  const int lr = l & 15, lk = l >> 4;
  const int rg = blockIdx.x, bg = blockIdx.y, z = blockIdx.z;
  const int ug2 = wv >> 1;
  const int g0 = (wv & 1) * 2;
  const int u16g = bg*2 + ug2;

  short8 whH[8][2], whL[8][2], wpH[2][2], wpL[2][2];
  #pragma unroll
  for (int s = 0; s < 8; ++s)
    #pragma unroll
    for (int c = 0; c < 2; ++c) {
      int ctg = u16g*4 + g0 + c;
      whH[s][c] = *(const short8*)(whhFL + ((size_t)(s*64 + ctg))*512 + l*8);
      whL[s][c] = *(const short8*)(whhFL + 262144 + ((size_t)(s*64 + ctg))*512 + l*8);
    }
  #pragma unroll
  for (int s = 0; s < 2; ++s)
    #pragma unroll
    for (int c = 0; c < 2; ++c) {
      int ctg = u16g*4 + g0 + c;
      wpH[s][c] = *(const short8*)(wpFL + ((size_t)(s*64 + ctg))*512 + l*8);
      wpL[s][c] = *(const short8*)(wpFL + 65536 + ((size_t)(s*64 + ctg))*512 + l*8);
    }
  const int ul = tid & 31, er0 = tid >> 5;
  float bb[4];
  #pragma unroll
  for (int g = 0; g < 4; ++g) bb[g] = bp[g*256 + bg*32 + ul];
  float cs[2] = {0.f, 0.f};

  u32* hz = henc + (size_t)z * (size_t)(T_+1) * HSTR;
  const float* xrow = x + ((size_t)(z*CBv + rg*16 + lr)*T_)*DIN_ + lk*8;

  for (int t = 0; t < T_; ++t) {
    float4 xv0 = *(const float4*)(xrow);
    float4 xv1 = *(const float4*)(xrow + 4);
    float4 xv2 = *(const float4*)(xrow + 32);
    float4 xv3 = *(const float4*)(xrow + 36);
    xrow += DIN_;

    const ull* hb = (const ull*)(hz + (size_t)t*HSTR + (size_t)(rg*16 + lr)*256);
    ull hq[8][4];
    #pragma unroll
    for (int s = 0; s < 8; ++s)
      #pragma unroll
      for (int q = 0; q < 4; ++q)
        hq[s][q] = __hip_atomic_load(hb + s*16 + lk*4 + q,
                                     __ATOMIC_RELAXED, __HIP_MEMORY_SCOPE_AGENT);
    if (t) {
      for (;;) {
        bool ok = true;
        #pragma unroll
        for (int s = 0; s < 8; ++s)
          #pragma unroll
          for (int q = 0; q < 4; ++q) {
            u32 a = (u32)hq[s][q], b = (u32)(hq[s][q] >> 32);
            ok = ok && (a != 0u) && (b != 0u);
          }
        if (__all(ok)) break;
        __builtin_amdgcn_s_sleep(1);
        #pragma unroll
        for (int s = 0; s < 8; ++s)
          #pragma unroll
          for (int q = 0; q < 4; ++q)
            hq[s][q] = __hip_atomic_load(hb + s*16 + lk*4 + q,
                                         __ATOMIC_RELAXED, __HIP_MEMORY_SCOPE_AGENT);
      }
    }

    f32x4 acc[2];
    acc[0] = (f32x4){0.f,0.f,0.f,0.f};
    acc[1] = (f32x4){0.f,0.f,0.f,0.f};

    #pragma unroll
    for (int s = 0; s < 2; ++s) {
      float vv[8];
      if (s == 0) { vv[0]=xv0.x;vv[1]=xv0.y;vv[2]=xv0.z;vv[3]=xv0.w;vv[4]=xv1.x;vv[5]=xv1.y;vv[6]=xv1.z;vv[7]=xv1.w; }
      else        { vv[0]=xv2.x;vv[1]=xv2.y;vv[2]=xv2.z;vv[3]=xv2.w;vv[4]=xv3.x;vv[5]=xv3.y;vv[6]=xv3.z;vv[7]=xv3.w; }
      short8 ah, al2;
      #pragma unroll
      for (int j = 0; j < 8; ++j) {
        u16 h = f2bf(vv[j]);
        ah[j] = (short)h;
        al2[j] = (short)f2bf(vv[j] - bf2f(h));
      }
      #pragma unroll
      for (int c = 0; c < 2; ++c) {
        acc[c] = __builtin_amdgcn_mfma_f32_16x16x32_bf16(ah,  wpH[s][c], acc[c], 0,0,0);
        acc[c] = __builtin_amdgcn_mfma_f32_16x16x32_bf16(al2, wpH[s][c], acc[c], 0,0,0);
        acc[c] = __builtin_amdgcn_mfma_f32_16x16x32_bf16(ah,  wpL[s][c], acc[c], 0,0,0);
      }
    }
    #pragma unroll
    for (int s = 0; s < 8; ++s) {
      short8 ah, al2;
      #pragma unroll
      for (int q = 0; q < 4; ++q) {
        u32 w0 = (u32)hq[s][q], w1 = (u32)(hq[s][q] >> 32);
        ah[q*2]   = (short)(w0 >> 16); al2[q*2]   = (short)(w0 & 0xffff);
        ah[q*2+1] = (short)(w1 >> 16); al2[q*2+1] = (short)(w1 & 0xffff);
      }
      #pragma unroll
      for (int c = 0; c < 2; ++c) {
        acc[c] = __builtin_amdgcn_mfma_f32_16x16x32_bf16(ah,  whH[s][c], acc[c], 0,0,0);
        acc[c] = __builtin_amdgcn_mfma_f32_16x16x32_bf16(al2, whH[s][c], acc[c], 0,0,0);
        acc[c] = __builtin_amdgcn_mfma_f32_16x16x32_bf16(ah,  whL[s][c], acc[c], 0,0,0);
      }
    }

    const int p = t & 1;
    #pragma unroll
    for (int c = 0; c < 2; ++c)
      #pragma unroll
      for (int j = 0; j < 4; ++j)
        G[p][lk*4 + j][ug2*16 + lr][g0 + c] = acc[c][j];
    __syncthreads();

    #pragma unroll
    for (int pp = 0; pp < 2; ++pp) {
      int row = er0 + pp*8;
      float4 gq = *(const float4*)&G[p][row][ul][0];
      float gi = gq.x + bb[0], gf = gq.y + bb[1];
      float gg = gq.z + bb[2], go = gq.w + bb[3];
      float cn = sigm(gf)*cs[pp] + sigm(gi)*tanhf(gg);
      float hn = sigm(go)*tanhf(cn);
      cs[pp] = cn;
      as_(hz + (size_t)(t+1)*HSTR + (size_t)(rg*16 + row)*256 + bg*32 + ul,
          packhl(hn) | 1u);
    }
  }
}

// ---------------------------------------------------------------------------
// MLP layer-loop core v2: 512 thr = 8 waves as 8 COL-GROUPS (no row split).
// Each wave: all 64 rows x its 32 cols (2 ct frags) -> B loaded exactly ONCE
// per block per layer (256KB, no rg duplication; halves L2 traffic).
// B triple-buffered (prefetch slab s+2). act: [64][256] u32 packhl swizzled.
// ---------------------------------------------------------------------------
static __device__ __forceinline__ void mlp_core(
    u32* act, const u16* wFL, const float* bs, const float* bl,
    int L, int nbs, bool lastRelu, int tid)
{
  const int l = tid & 63, cg = tid >> 6;       // wave = col-group 0..7
  const int lr = l & 15, lk = l >> 4;
  f32x4 acc[4][2];
  for (int lyr = 0; lyr < L; ++lyr) {
    __syncthreads();
    const u16* wb = wFL + (size_t)lyr*131072;
    #pragma unroll
    for (int rt = 0; rt < 4; ++rt)
      #pragma unroll
      for (int ct = 0; ct < 2; ++ct) acc[rt][ct] = (f32x4){0.f,0.f,0.f,0.f};

    short8 bh[3][2], blo[3][2];
    #pragma unroll
    for (int pre = 0; pre < 2; ++pre)
      #pragma unroll
      for (int ct = 0; ct < 2; ++ct) {
        const u16* bfp = wb + ((size_t)(pre*16 + cg*2 + ct))*512 + l*8;
        bh[pre][ct]  = *(const short8*)bfp;
        blo[pre][ct] = *(const short8*)(bfp + 65536);
      }
    #pragma unroll
    for (int s = 0; s < 8; ++s) {
      const int cur = s % 3, nxt = (s + 2) % 3;
      if (s < 6) {
        #pragma unroll
        for (int ct = 0; ct < 2; ++ct) {
          const u16* bfp = wb + ((size_t)((s+2)*16 + cg*2 + ct))*512 + l*8;
          bh[nxt][ct]  = *(const short8*)bfp;
          blo[nxt][ct] = *(const short8*)(bfp + 65536);
        }
      }
      short8 ah[4], al2[4];
      #pragma unroll
      for (int rt = 0; rt < 4; ++rt) {
        int row = rt*16 + lr;
        int cc = s*8 + lk*2;
        const u32* base = act + row*256;
        uint4 d0 = *(const uint4*)(base + (((cc    ) ^ (row & 7)) << 2));
        uint4 d1 = *(const uint4*)(base + (((cc + 1) ^ (row & 7)) << 2));
        u32 q[8] = {d0.x,d0.y,d0.z,d0.w,d1.x,d1.y,d1.z,d1.w};
        #pragma unroll
        for (int j = 0; j < 8; ++j) {
          ah[rt][j]  = (short)(q[j] >> 16);
          al2[rt][j] = (short)(q[j] & 0xffff);
        }
      }
      #pragma unroll
      for (int ct = 0; ct < 2; ++ct)
        #pragma unroll
        for (int rt = 0; rt < 4; ++rt) {
          acc[rt][ct] = __builtin_amdgcn_mfma_f32_16x16x32_bf16(ah[rt],  bh[cur][ct],  acc[rt][ct], 0,0,0);
          acc[rt][ct] = __builtin_amdgcn_mfma_f32_16x16x32_bf16(al2[rt], bh[cur][ct],  acc[rt][ct], 0,0,0);
          acc[rt][ct] = __builtin_amdgcn_mfma_f32_16x16x32_bf16(ah[rt],  blo[cur][ct], acc[rt][ct], 0,0,0);
        }
    }
    const float* bptr = (lyr < nbs) ? (bs + lyr*256) : bl;
    const bool dorelu = (lyr < L-1) || lastRelu;
    #pragma unroll
    for (int ct = 0; ct < 2; ++ct) {
      float bv = bptr[cg*32 + ct*16 + lr];
      #pragma unroll
      for (int rt = 0; rt < 4; ++rt)
        #pragma unroll
        for (int g = 0; g < 4; ++g) {
          float xv = acc[rt][ct][g] + bv;
          acc[rt][ct][g] = dorelu ? fmaxf(xv, 0.f) : xv;
        }
    }
    __syncthreads();
    #pragma unroll
    for (int ct = 0; ct < 2; ++ct) {
      int n = cg*32 + ct*16 + lr;
      #pragma unroll
      for (int rt = 0; rt < 4; ++rt)
        #pragma unroll
        for (int g = 0; g < 4; ++g) {
          int row = rt*16 + lk*4 + g;
          act[row*256 + (((n >> 2) ^ (row & 7)) << 2) + (n & 3)] = packhl(acc[rt][ct][g]);
        }
    }
  }
  __syncthreads();
}

// ---------------------------------------------------------------------------
// MEGA decode kernel, 512 thr, 128KB LDS (act 64KB + usL 64KB).
// whsP != nullptr: whs precomputed once; else per-step recompute.
// ---------------------------------------------------------------------------
__global__ __launch_bounds__(512,1) void k_dec_all(
    const u32* __restrict__ henc, const u16* __restrict__ mlpFL,
    const float* __restrict__ wbs, const float* __restrict__ wbl,
    const float* __restrict__ ubs, const float* __restrict__ ubl,
    const float* __restrict__ vbs, const float* __restrict__ vWl,
    const float* __restrict__ vbl,
    const float* __restrict__ dWt, const float* __restrict__ dbih,
    const float* __restrict__ dbhh,
    const float* __restrict__ oW, const float* __restrict__ ob,
    u32* __restrict__ whsP,
    u32* __restrict__ eS, u32* __restrict__ ctxS, u32* __restrict__ sS,
    float* __restrict__ outc)
{
  extern __shared__ u32 act[];            // [16384] act + [16384] usL
  __shared__ float red[8], red2[8];
  const int bid = blockIdx.x, tid = threadIdx.x;
  u32* usL = act + 16384;
  const u16* wFLw = mlpFL;
  const u16* wFLu = mlpFL + 4*131072;
  const u16* wFLv = mlpFL + 8*131072;
  const int half = bid & 1;
  const bool useW = (whsP != nullptr);
  float sprev[4] = {0.f, 0.f, 0.f, 0.f};

  // ======== whs precompute (once): 4 block-local tiles -> whsP ========
  if (useW) {
    for (int k = 0; k < 4; ++k) {
      long m0t = (long)(bid + 256*k) * 64;
      __syncthreads();
      for (int i = tid; i < 4096; i += 512) {
        int row = i >> 6, c16 = i & 63;
        uint4 pk = *(const uint4*)(henc + HSTR + (m0t + row)*256 + c16*4);
        *((uint4*)(act + row*256 + ((c16 ^ (row & 7)) << 2))) = pk;
      }
      mlp_core(act, wFLw, wbs, wbl, 4, 3, false, tid);
      for (int i = tid; i < 4096; i += 512) {
        int row = i >> 6, c16 = i & 63;
        uint4 pk = *((const uint4*)(act + row*256 + ((c16 ^ (row & 7)) << 2)));
        *(uint4*)(whsP + (m0t + row)*256 + c16*4) = pk;
      }
    }
  }

  // ======== decode steps ========
  for (int s = 0; s < OL_; ++s) {
    // ---- u-phase: ALL blocks compute their us-half locally
    __syncthreads();                      // prior-step LDS uses complete
    for (int i = tid; i < 4096; i += 512) {
      int row = i >> 6, c16 = i & 63;
      uint4 pk;
      if (s) {
        const u32* sp = sS + (size_t)s*32768 + (size_t)(half*64 + row)*256 + c16*4;
        u32 w0 = al(sp), w1 = al(sp+1), w2 = al(sp+2), w3 = al(sp+3);
        while (!(w0 && w1 && w2 && w3)) {
          __builtin_amdgcn_s_sleep(1);
          w0 = al(sp); w1 = al(sp+1); w2 = al(sp+2); w3 = al(sp+3);
        }
        pk = (uint4){ packhl(__uint_as_float(w0)), packhl(__uint_as_float(w1)),
                      packhl(__uint_as_float(w2)), packhl(__uint_as_float(w3)) };
      } else {
        pk = (uint4){0u, 0u, 0u, 0u};     // s0 = 0
      }
      *((uint4*)(act + row*256 + ((c16 ^ (row & 7)) << 2))) = pk;
    }
    mlp_core(act, wFLu, ubs, ubl, 4, 3, false, tid);
    for (int i = tid; i < 16384; i += 512) usL[i] = act[i];   // verbatim copy

    // ---- v-phase: 4 tiles
    for (int k = 0; k < 4; ++k) {
      long m0t = (long)(bid + 256*k) * 64;
      __syncthreads();                    // usL copy done / act free
      if (useW) {
        for (int i = tid; i < 4096; i += 512) {
          int row = i >> 6, c16 = i & 63;
          uint4 pw = *(const uint4*)(whsP + (m0t + row)*256 + c16*4);
          u32* dst = act + row*256 + ((c16 ^ (row & 7)) << 2);
          const u32* uw = usL + row*256 + ((c16 ^ (row & 7)) << 2);
          dst[0] = packhl(tanhf(unpackhl(pw.x) + unpackhl(uw[0])));
          dst[1] = packhl(tanhf(unpackhl(pw.y) + unpackhl(uw[1])));
          dst[2] = packhl(tanhf(unpackhl(pw.z) + unpackhl(uw[2])));
          dst[3] = packhl(tanhf(unpackhl(pw.w) + unpackhl(uw[3])));
        }
      } else {
        for (int i = tid; i < 4096; i += 512) {
          int row = i >> 6, c16 = i & 63;
          uint4 pk = *(const uint4*)(henc + HSTR + (m0t + row)*256 + c16*4);
          *((uint4*)(act + row*256 + ((c16 ^ (row & 7)) << 2))) = pk;
        }
        mlp_core(act, wFLw, wbs, wbl, 4, 3, false, tid);   // whs tile
        for (int i = tid; i < 16384; i += 512) {
          u32 a = act[i], u = usL[i];
          act[i] = packhl(tanhf(unpackhl(a) + unpackhl(u)));
        }
      }
      mlp_core(act, wFLv, vbs, vbs, 7, 7, true, tid);      // 7 relu layers
      // e-dot: 8 threads per row (32 cols each)
      {
        int r2 = tid >> 3, q = tid & 7;
        float p = 0.f;
        #pragma unroll 8
        for (int j = 0; j < 32; ++j) {
          int n = q*32 + j;
          u32 w = act[r2*256 + (((n >> 2) ^ (r2 & 7)) << 2) + (n & 3)];
          p += unpackhl(w) * vWl[n];
        }
        p += __shfl_xor(p, 1, 64);
        p += __shfl_xor(p, 2, 64);
        p += __shfl_xor(p, 4, 64);
        if (q == 0)
          as_(eS + (size_t)s*65536 + m0t + r2, __float_as_uint(p + vbl[0]) | 1u);
      }
    }

    // ---- attn (blocks 64..191): row b = bid-64
    if (bid >= 64 && bid < 192) {
      int b = bid - 64;
      __syncthreads();                    // reclaim act
      float* asx = (float*)act;           // [512] weights + [512] partials
      const u32* ep0 = eS + (size_t)s*65536 + b;
      u32 w0;
      for (;;) {
        w0 = al(ep0 + (size_t)tid*128);
        if (w0) break;
        __builtin_amdgcn_s_sleep(1);
      }
      float v0 = __uint_as_float(w0);
      const int lane = tid & 63, wv = tid >> 6;
      float m = v0;
      #pragma unroll
      for (int o = 32; o; o >>= 1) m = fmaxf(m, __shfl_xor(m, o, 64));
      if (!lane) red[wv] = m;
      __syncthreads();
      m = fmaxf(fmaxf(fmaxf(red[0], red[1]), fmaxf(red[2], red[3])),
                fmaxf(fmaxf(red[4], red[5]), fmaxf(red[6], red[7])));
      float x0 = expf(v0 - m);
      float sm = x0;
      #pragma unroll
      for (int o = 32; o; o >>= 1) sm += __shfl_xor(sm, o, 64);
      if (!lane) red2[wv] = sm;
      __syncthreads();
      float inv = 1.f / (red2[0] + red2[1] + red2[2] + red2[3]
                       + red2[4] + red2[5] + red2[6] + red2[7]);
      asx[tid] = x0 * inv;
      __syncthreads();
      int unit = tid & 255, hf = tid >> 8;
      float accv = 0.f;
      const u32* hp = henc + HSTR + (size_t)b*256 + unit;
      #pragma unroll 8
      for (int t = hf*256; t < hf*256 + 256; ++t)
        accv += asx[t] * unpackhl(hp[(size_t)t*HSTR]);
      float* part = asx + 512;
      part[tid] = accv;
      __syncthreads();
      if (hf == 0)
        as_(ctxS + (size_t)s*32768 + b*256 + unit,
            __float_as_uint(accv + part[256 + unit]) | 1u);
    }

    // ---- cell + outproj (blocks 224..255): rows 4c..4c+3
    if (bid >= 224) {
      int c = bid - 224, b0r = c*4;
      __syncthreads();                    // reclaim act
      float* xt = (float*)act;            // [4][520]
      const int u = tid & 255, kh = tid >> 8;
      if (kh == 0) {
        const u32* cp = ctxS + (size_t)s*32768 + (size_t)b0r*256 + u;
        u32 w0, w1, w2, w3;
        for (;;) {
          w0 = al(cp); w1 = al(cp + 256); w2 = al(cp + 512); w3 = al(cp + 768);
          if (w0 && w1 && w2 && w3) break;
          __builtin_amdgcn_s_sleep(1);
        }
        xt[0*520 + u] = __uint_as_float(w0);
        xt[1*520 + u] = __uint_as_float(w1);
        xt[2*520 + u] = __uint_as_float(w2);
        xt[3*520 + u] = __uint_as_float(w3);
        #pragma unroll
        for (int bb = 0; bb < 4; ++bb) xt[bb*520 + 256 + u] = sprev[bb];
      }
      __syncthreads();
      float ai[4], ag[4], ao[4];
      #pragma unroll
      for (int bb = 0; bb < 4; ++bb) { ai[bb]=0.f; ag[bb]=0.f; ao[bb]=0.f; }
      #pragma unroll 4
      for (int k = kh*256; k < kh*256 + 256; ++k) {
        float wi = dWt[k*768 + u];
        float wg = dWt[k*768 + 256 + u];
        float wo = dWt[k*768 + 512 + u];
        #pragma unroll
        for (int bb = 0; bb < 4; ++bb) {
          float xv = xt[bb*520 + k];
          ai[bb] += xv*wi; ag[bb] += xv*wg; ao[bb] += xv*wo;
        }
      }
      float* pr = xt + 4*520;             // partials [3][4][256]
      if (kh) {
        #pragma unroll
        for (int bb = 0; bb < 4; ++bb) {
          pr[(0*4 + bb)*256 + u] = ai[bb];
          pr[(1*4 + bb)*256 + u] = ag[bb];
          pr[(2*4 + bb)*256 + u] = ao[bb];
        }
      }
      __syncthreads();
      float* sn = pr + 3*4*256;           // [4][256]
      if (!kh) {
        float bi = dbih[u]       + dbhh[u];
        float bg = dbih[512 + u] + dbhh[512 + u];
        float bo = dbih[768 + u] + dbhh[768 + u];
        #pragma unroll
        for (int bb = 0; bb < 4; ++bb) {
          float a1 = ai[bb] + pr[(0*4 + bb)*256 + u];
          float g1 = ag[bb] + pr[(1*4 + bb)*256 + u];
          float o1 = ao[bb] + pr[(2*4 + bb)*256 + u];
          float cn = sigm(a1 + bi) * tanhf(g1 + bg);
          float hn = sigm(o1 + bo) * tanhf(cn);
          as_(sS + (size_t)(s+1)*32768 + (size_t)(b0r + bb)*256 + u,
              __float_as_uint(hn) | 1u);
          sprev[bb] = hn;
          sn[bb*256 + u] = hn;
        }
      }
      __syncthreads();
      if (tid < 256) {
        int d = tid & 63, rr = tid >> 6;
        float a2 = ob[d];
        #pragma unroll 4
        for (int k = 0; k < 256; ++k) a2 += sn[rr*256 + k] * oW[k*64 + d];
        outc[((size_t)(b0r + rr)*OL_ + s)*64 + d] = a2;
      }
    }
  }
}

// ---------------------------------------------------------------------------
extern "C" void kernel_launch(void* const* d_in, const int* in_sizes, int n_in,
                              void* d_out, int out_size, void* d_ws, size_t ws_size,
                              hipStream_t stream)
{
  (void)in_sizes; (void)n_in;
  const float* x    = (const float*)d_in[0];
  const float* inW  = (const float*)d_in[1];
  const float* inb  = (const float*)d_in[2];
  const float* eWih = (const float*)d_in[3];
  const float* eWhh = (const float*)d_in[4];
  const float* ebih = (const float*)d_in[5];
  const float* ebhh = (const float*)d_in[6];
  const float* dWih = (const float*)d_in[7];
  const float* dbih = (const float*)d_in[9];
  const float* dbhh = (const float*)d_in[10];
  const float* wWs  = (const float*)d_in[11];
  const float* wbs  = (const float*)d_in[12];
  const float* wWl  = (const float*)d_in[13];
  const float* wbl  = (const float*)d_in[14];
  const float* uWs  = (const float*)d_in[15];
  const float* ubs  = (const float*)d_in[16];
  const float* uWl  = (const float*)d_in[17];
  const float* ubl  = (const float*)d_in[18];
  const float* vWs  = (const float*)d_in[19];
  const float* vbs  = (const float*)d_in[20];
  const float* vWl  = (const float*)d_in[21];
  const float* vbl  = (const float*)d_in[22];
  const float* oW   = (const float*)d_in[23];
  const float* ob   = (const float*)d_in[24];
  float* out = (float*)d_out;

  hipFuncSetAttribute((const void*)k_dec_all, hipFuncAttributeMaxDynamicSharedMemorySize, 131072);

  const size_t hsz = (size_t)(T_+1) * HSTR;     // u32 per chunk
  const size_t avail = ws_size / 4;
  const size_t scratchU = 524288ull + 262144 + 294912;   // eS + ctxS + sS
  const size_t prepsU = 1770496ull;
  auto needf = [&](int nc, int usewhs) -> size_t {
    return (size_t)nc*hsz + (usewhs ? 16777216ull : 0ull) + scratchU + prepsU + 4096;
  };
  int NC = 1, USEW = 0;
  if      (needf(4,1) <= avail) { NC = 4; USEW = 1; }   // 348 MB
  else if (needf(4,0) <= avail) { NC = 4; USEW = 0; }   // 280 MB
  else if (needf(2,1) <= avail) { NC = 2; USEW = 1; }   // 213 MB (known-good)
  else if (needf(1,1) <= avail) { NC = 1; USEW = 1; }   // 150 MB
  else if (needf(1,0) <= avail) { NC = 1; USEW = 0; }   // 133 MB
  else { hipMemsetAsync(d_out, 0, (size_t)out_size*4, stream); return; }

  float* wsf = (float*)d_ws;
  size_t o = 0;
  u32* henc = (u32*)(wsf + o);  o += (size_t)NC*hsz;
  u32* whsP = nullptr;
  if (USEW) { whsP = (u32*)(wsf + o);  o += 16777216; }
  u32* eS   = (u32*)(wsf + o);  o += 524288;       // scratch block start
  u32* ctxS = (u32*)(wsf + o);  o += 262144;
  u32* sS   = (u32*)(wsf + o);  o += 294912;       // scratch block end
  float* WpT = wsf + o;  o += 65536;
  float* bp  = wsf + o;  o += 1024;
  float* dWt = wsf + o;  o += 393216;
  u16* whhFL = (u16*)(wsf + o);  o += 262144;
  u16* wpFL  = (u16*)(wsf + o);  o += 65536;
  u16* mlpFL = (u16*)(wsf + o);                    // 983040 float-units

  const size_t scratchBytes = scratchU * 4;

  // ---- weight preps (chunk-invariant)
  k_wpt<<<256, 256, 0, stream>>>(inW, eWih, WpT);
  k_bp <<<4,   256, 0, stream>>>(inb, eWih, ebih, ebhh, bp);
  k_dwt<<<1536,256, 0, stream>>>(dWih, dWt);
  k_whhfl<<<1024,256,0,stream>>>(eWhh, whhFL);
  k_wpfl <<<256, 256,0,stream>>>(WpT, wpFL);
  k_wall <<<dim3(256,15), 256, 0, stream>>>(wWs, wWl, uWs, uWl, vWs, mlpFL);

  for (int c0 = 0; c0 < B_; c0 += CBv*NC) {
    hipMemsetAsync(henc, 0, (size_t)NC*hsz*4, stream);   // data-as-flag: clean

    // concurrent chunk encoders
    k_enc<<<dim3(CBv/16, 8, NC), 256, 0, stream>>>(
        x + (size_t)c0*T_*DIN_, whhFL, wpFL, bp, henc);

    for (int z = 0; z < NC; ++z) {
      hipMemsetAsync(eS, 0, scratchBytes, stream);       // step-flags clean
      k_dec_all<<<256, 512, 131072, stream>>>(
          henc + (size_t)z*hsz, mlpFL,
          wbs, wbl, ubs, ubl, vbs, vWl, vbl,
          dWt, dbih, dbhh, oW, ob,
          whsP, eS, ctxS, sS,
          out + (size_t)(c0 + z*CBv)*OL_*DOUT_);
    }
  }
}